// Round 16
// baseline (246.609 us; speedup 1.0000x reference)
//
#include <hip/hip_runtime.h>

typedef unsigned short u16;
typedef __attribute__((ext_vector_type(8))) __bf16 bf16x8;
typedef __attribute__((ext_vector_type(4))) float f32x4;

#define MFMA16(a, b, c) __builtin_amdgcn_mfma_f32_16x16x32_bf16((a), (b), (c), 0, 0, 0)

#if __has_builtin(__builtin_amdgcn_exp2f)
#define EXP2(x) __builtin_amdgcn_exp2f(x)
#else
#define EXP2(x) exp2f(x)
#endif
#define LOG2E 1.44269504088896f

__device__ __forceinline__ u16 f2bf(float f) {
  union { float f; unsigned u; } c; c.f = f;
  unsigned u = c.u;
  u += 0x7FFFu + ((u >> 16) & 1u);   // round-to-nearest-even
  return (u16)(u >> 16);
}

// native float->bf16 (compiler lowers to HW cvt, RTNE — fast path per m240)
__device__ __forceinline__ u16 cvtbf(float f) {
  union { __bf16 b; u16 u; } c;
  c.b = (__bf16)f;
  return c.u;
}

__device__ __forceinline__ bf16x8 pack8(const float4& a, const float4& b) {
  union { u16 u[8]; bf16x8 v; } r;
  r.u[0] = f2bf(a.x); r.u[1] = f2bf(a.y); r.u[2] = f2bf(a.z); r.u[3] = f2bf(a.w);
  r.u[4] = f2bf(b.x); r.u[5] = f2bf(b.y); r.u[6] = f2bf(b.z); r.u[7] = f2bf(b.w);
  return r.v;
}

// async global->LDS, 16 bytes/lane (LDS dest = base + tid*16, m104 constraint).
__device__ __forceinline__ void async_cp16(u16* l, const u16* g) {
  __builtin_amdgcn_global_load_lds(
      (const __attribute__((address_space(1))) unsigned int*)g,
      (__attribute__((address_space(3))) unsigned int*)l, 16, 0, 0);
}

// ---------------------------------------------------------------------------
// X fp32 -> bf16 (elementwise, once). Values identical to pack8's f2bf.
// ---------------------------------------------------------------------------
__global__ __launch_bounds__(256) void xcvt_k(const float* __restrict__ Xf,
                                              u16* __restrict__ Xb) {
  const size_t i = ((size_t)blockIdx.x * 256 + threadIdx.x) * 8;
  float4 a = *(const float4*)(Xf + i);
  float4 b = *(const float4*)(Xf + i + 4);
  *(bf16x8*)(Xb + i) = pack8(a, b);
}

// ---------------------------------------------------------------------------
// Fused weight transpose+cvt: 4 slices in one launch (grid.z selects slice).
// ---------------------------------------------------------------------------
__global__ __launch_bounds__(256) void transpose_all_k(
    const float* __restrict__ Wq, const float* __restrict__ Wkv,
    const float* __restrict__ Wo, u16* __restrict__ Wall,
    u16* __restrict__ WoT) {
  __shared__ u16 t[32][33];
  const int z = blockIdx.z;
  const float* src; u16* dst; int C_ld, col0;
  if (z == 0)      { src = Wo;  dst = WoT;                C_ld = 1024; col0 = 0; }
  else if (z == 1) { src = Wq;  dst = Wall;               C_ld = 1024; col0 = 0; }
  else if (z == 2) { src = Wkv; dst = Wall + 1024 * 1024; C_ld = 2048; col0 = 0; }
  else             { src = Wkv; dst = Wall + 2048 * 1024; C_ld = 2048; col0 = 1024; }
  const int bx = blockIdx.x * 32;
  const int by = blockIdx.y * 32;
  const int tx = threadIdx.x;
  for (int yo = threadIdx.y; yo < 32; yo += 8)
    t[yo][tx] = f2bf(src[(size_t)(by + yo) * C_ld + col0 + bx + tx]);
  __syncthreads();
  for (int yo = threadIdx.y; yo < 32; yo += 8)
    dst[(size_t)(bx + yo) * 1024 + by + tx] = t[tx][yo];
}

// ---------------------------------------------------------------------------
// T5 bias table: tab[delta + 2047][h], delta = j - i.
// R16: values pre-multiplied by LOG2E — attn softmax runs in exp2 domain
// (base-invariant: numerator and denominator use the same P, factors cancel).
// ---------------------------------------------------------------------------
__global__ void bias_table_k(const float* __restrict__ rel_emb, float* __restrict__ tab) {
  int idx = blockIdx.x * blockDim.x + threadIdx.x;
  if (idx >= 4095) return;
  int delta = idx - 2047;   // j - i
  int n = -delta;           // i - j
  int ret = 0;
  if (n < 0) { ret = 16; n = -n; }
  int bucket;
  if (n < 8) {
    bucket = n;
  } else {
    int vl = 8 + (int)(2.0f * __log2f((float)n * 0.125f));
    bucket = vl < 15 ? vl : 15;
  }
  bucket += ret;
#pragma unroll
  for (int h = 0; h < 16; h++)
    tab[(size_t)idx * 16 + h] = rel_emb[bucket * 16 + h] * LOG2E;
}

// ---------------------------------------------------------------------------
// Shared epilogue for both proj variants.
// ---------------------------------------------------------------------------
__device__ __forceinline__ void proj_epilogue(
    const f32x4 (&acc)[4][4], int m0, int n0, int wr, int wc, int lane,
    u16* dstQ, u16* dstK, u16* dstVT) {
  const int orow = (lane >> 4) * 4, ocol = lane & 15;
#pragma unroll
  for (int i = 0; i < 4; i++)
#pragma unroll
    for (int j = 0; j < 4; j++)
#pragma unroll
      for (int r = 0; r < 4; r++) {
        int grow = m0 + wr + i * 16 + orow + r;   // token
        int gcol = n0 + wc + j * 16 + ocol;       // fused channel 0..3071
        int b = grow >> 11, n = grow & 2047;
        int seg = gcol >> 10;                     // 0=Q, 1=K, 2=V (uniform/block)
        int c = gcol & 1023;
        int h = c >> 6, d = c & 63;
        u16 bv = f2bf(acc[i][j][r]);
        if (seg == 0)
          dstQ[(((size_t)b * 16 + h) * 2048 + n) * 64 + d] = bv;
        else if (seg == 1)
          dstK[(((size_t)b * 16 + h) * 2048 + n) * 64 + d] = bv;
        else
          dstVT[(((size_t)b * 16 + h) * 64 + d) * 2048 + n] = bv;
      }
}

// ---------------------------------------------------------------------------
// Fast projection GEMM: Xb(4096x1024 bf16, pre-converted) @ Wall^T.
// ---------------------------------------------------------------------------
__global__ __launch_bounds__(256) void proj_gemm_bf16_k(
    const u16* __restrict__ Xb, const u16* __restrict__ WT,
    u16* __restrict__ dstQ, u16* __restrict__ dstK, u16* __restrict__ dstVT) {
  __shared__ __align__(16) u16 As[2][128 * 32];
  __shared__ __align__(16) u16 Bs[2][128 * 32];
  f32x4 acc[4][4];
#pragma unroll
  for (int i = 0; i < 4; i++)
#pragma unroll
    for (int j = 0; j < 4; j++) acc[i][j] = f32x4{0.f, 0.f, 0.f, 0.f};

  const int m0 = blockIdx.x * 128;
  const int n0 = blockIdx.y * 128;
  const int tid  = threadIdx.x;
  const int lane = tid & 63;
  const int wave = tid >> 6;
  const int wr = (wave >> 1) * 64;
  const int wc = (wave & 1) * 64;
  const int lr = lane & 15;
  const int lk = (lane >> 4) * 8;
  const int r0 = tid >> 2;
  const int sg = (tid & 3) * 8;

  const u16* xp0 = Xb + (size_t)(m0 + r0) * 1024 + sg;
  const u16* xp1 = Xb + (size_t)(m0 + 64 + r0) * 1024 + sg;
  const u16* bp0 = WT + (size_t)(n0 + r0) * 1024 + sg;
  const u16* bp1 = WT + (size_t)(n0 + 64 + r0) * 1024 + sg;
  const int ao0 = r0 * 32 + sg;            // byte off within buffer = tid*16
  const int ao1 = (64 + r0) * 32 + sg;
  const int bo0 = ao0, bo1 = ao1;

  async_cp16(&As[0][ao0], xp0);
  async_cp16(&As[0][ao1], xp1);
  async_cp16(&Bs[0][bo0], bp0);
  async_cp16(&Bs[0][bo1], bp1);
  __syncthreads();

  int cur = 0;
  for (int k0 = 0; k0 < 1024; k0 += 32) {
    const int nxt = cur ^ 1;
    const int kn = k0 + 32;
    const bool have_next = (kn < 1024);
    if (have_next) {
      async_cp16(&As[nxt][ao0], xp0 + kn);
      async_cp16(&As[nxt][ao1], xp1 + kn);
      async_cp16(&Bs[nxt][bo0], bp0 + kn);
      async_cp16(&Bs[nxt][bo1], bp1 + kn);
    }
    bf16x8 af[4], bfv[4];
#pragma unroll
    for (int i = 0; i < 4; i++)
      af[i] = *(const bf16x8*)&As[cur][(wr + i * 16 + lr) * 32 + lk];
#pragma unroll
    for (int j = 0; j < 4; j++)
      bfv[j] = *(const bf16x8*)&Bs[cur][(wc + j * 16 + lr) * 32 + lk];
#pragma unroll
    for (int i = 0; i < 4; i++)
#pragma unroll
      for (int j = 0; j < 4; j++)
        acc[i][j] = MFMA16(af[i], bfv[j], acc[i][j]);
    __syncthreads();
    cur = nxt;
  }
  proj_epilogue(acc, m0, n0, wr, wc, lane, dstQ, dstK, dstVT);
}

// ---------------------------------------------------------------------------
// Fallback projection GEMM (verified): Xf fp32 A-path with pack8 staging.
// ---------------------------------------------------------------------------
__global__ __launch_bounds__(256) void proj_gemm_f32_k(
    const float* __restrict__ Xf, const u16* __restrict__ WT,
    u16* __restrict__ dstQ, u16* __restrict__ dstK, u16* __restrict__ dstVT) {
  __shared__ __align__(16) u16 As[2][128 * 32];
  __shared__ __align__(16) u16 Bs[2][128 * 32];
  f32x4 acc[4][4];
#pragma unroll
  for (int i = 0; i < 4; i++)
#pragma unroll
    for (int j = 0; j < 4; j++) acc[i][j] = f32x4{0.f, 0.f, 0.f, 0.f};

  const int m0 = blockIdx.x * 128;
  const int n0 = blockIdx.y * 128;
  const int tid  = threadIdx.x;
  const int lane = tid & 63;
  const int wave = tid >> 6;
  const int wr = (wave >> 1) * 64;
  const int wc = (wave & 1) * 64;
  const int lr = lane & 15;
  const int lk = (lane >> 4) * 8;
  const int r0 = tid >> 2;
  const int sg = (tid & 3) * 8;

  const float* ap0 = Xf + (size_t)(m0 + r0) * 1024 + sg;
  const float* ap1 = Xf + (size_t)(m0 + 64 + r0) * 1024 + sg;
  const u16* bp0 = WT + (size_t)(n0 + r0) * 1024 + sg;
  const u16* bp1 = WT + (size_t)(n0 + 64 + r0) * 1024 + sg;
  const int ao0 = r0 * 32 + sg;
  const int ao1 = (64 + r0) * 32 + sg;
  const int bo0 = ao0, bo1 = ao1;

  async_cp16(&Bs[0][bo0], bp0);
  async_cp16(&Bs[0][bo1], bp1);
  {
    float4 a00 = *(const float4*)(ap0);
    float4 a01 = *(const float4*)(ap0 + 4);
    float4 a10 = *(const float4*)(ap1);
    float4 a11 = *(const float4*)(ap1 + 4);
    *(bf16x8*)&As[0][ao0] = pack8(a00, a01);
    *(bf16x8*)&As[0][ao1] = pack8(a10, a11);
  }
  __syncthreads();

  int cur = 0;
  for (int k0 = 0; k0 < 1024; k0 += 32) {
    const int nxt = cur ^ 1;
    const int kn = k0 + 32;
    const bool have_next = (kn < 1024);
    float4 a00, a01, a10, a11;
    if (have_next) {
      async_cp16(&Bs[nxt][bo0], bp0 + kn);
      async_cp16(&Bs[nxt][bo1], bp1 + kn);
      a00 = *(const float4*)(ap0 + kn);
      a01 = *(const float4*)(ap0 + kn + 4);
      a10 = *(const float4*)(ap1 + kn);
      a11 = *(const float4*)(ap1 + kn + 4);
    }
    bf16x8 af[4], bfv[4];
#pragma unroll
    for (int i = 0; i < 4; i++)
      af[i] = *(const bf16x8*)&As[cur][(wr + i * 16 + lr) * 32 + lk];
#pragma unroll
    for (int j = 0; j < 4; j++)
      bfv[j] = *(const bf16x8*)&Bs[cur][(wc + j * 16 + lr) * 32 + lk];
#pragma unroll
    for (int i = 0; i < 4; i++)
#pragma unroll
      for (int j = 0; j < 4; j++)
        acc[i][j] = MFMA16(af[i], bfv[j], acc[i][j]);
    if (have_next) {
      *(bf16x8*)&As[nxt][ao0] = pack8(a00, a01);
      *(bf16x8*)&As[nxt][ao1] = pack8(a10, a11);
    }
    __syncthreads();
    cur = nxt;
  }
  proj_epilogue(acc, m0, n0, wr, wc, lane, dstQ, dstK, dstVT);
}

// ---------------------------------------------------------------------------
// Flash attention with T5 bias.
// Block = 128 Q-rows (two 64-row tiles) of one (b,h), 8 waves; ONE barrier
// per K-iteration; K/V/Bls double-buffered; split staging; MFMA-ones
// denominator (R15 structure — verified 105.3 µs).
// R16 (isolated VALU-diet pair):
//   (1) exp2-domain: bias tab is xLOG2E, scale2 = 0.125*LOG2E (same fused
//       FMA), P/alpha via native v_exp_f32 (2^x) — removes the x*log2e mul
//       inside every __expf. Softmax is base-invariant; same P feeds num
//       and denom, so values match up to f32 rounding placement.
//   (2) native (__bf16) casts for Ps/AO stores (HW cvt, RTNE) instead of
//       3-op manual f2bf.
// ---------------------------------------------------------------------------
__global__ __launch_bounds__(512) void attn_k(
    const u16* __restrict__ Q, const u16* __restrict__ Kb,
    const u16* __restrict__ VT, const float* __restrict__ bias_tab,
    u16* __restrict__ AO) {
  const int tid = threadIdx.x;                  // 0..511
  const int lane = tid & 63, wave = tid >> 6;   // wave 0..7
  const int t = wave >> 2;                      // q-subtile 0/1
  const int ws = wave & 3;                      // wave index within tile
  const int lr = lane & 15, lq = lane >> 4, lk = lq * 8;
  const int bh = blockIdx.y, b = bh >> 4, h = bh & 15;
  const int q0A = blockIdx.x * 128;             // tile-0 origin
  const int q0 = q0A + t * 64;                  // this wave's tile origin

  __shared__ __align__(16) u16 Qs[2][64 * 72];  // reused as Ps after Q-frag read
  __shared__ __align__(16) u16 Ks[2][64 * 72];  // [buf]
  __shared__ __align__(16) u16 Vs[2][64 * 72];  // [buf]
  __shared__ float Bls[2][2][128];              // [buf][tile]
  u16 (*Ps)[64 * 72] = Qs;

  const u16* Qg = Q + ((size_t)bh * 2048 + q0A) * 64;
  const u16* Kg = Kb + (size_t)bh * 2048 * 64;
  const u16* Vg = VT + (size_t)bh * 64 * 2048;
  const int ra = tid >> 3, sa = (tid & 7) * 8;

  // all-ones B fragment for the MFMA row-sum (bf16 1.0 = 0x3F80)
  union { u16 u[8]; bf16x8 v; } onesc;
#pragma unroll
  for (int i = 0; i < 8; i++) onesc.u[i] = 0x3F80;
  const bf16x8 onesv = onesc.v;

  // --- prologue: stage Q (both tiles) and K/V/Bls buffer 0 ---
  {
    int c1 = tid + 512;
    int r1_ = c1 >> 3, s1_ = (c1 & 7) * 8;      // r1_ 64..127 (tile 1)
    *(bf16x8*)(&Qs[0][ra * 72 + sa])          = *(const bf16x8*)(Qg + (size_t)ra * 64 + sa);
    *(bf16x8*)(&Qs[1][(r1_ - 64) * 72 + s1_]) = *(const bf16x8*)(Qg + (size_t)r1_ * 64 + s1_);
    *(bf16x8*)(&Ks[0][ra * 72 + sa]) = *(const bf16x8*)(Kg + (size_t)ra * 64 + sa);
    *(bf16x8*)(&Vs[0][ra * 72 + sa]) = *(const bf16x8*)(Vg + (size_t)ra * 2048 + sa);
    if (tid < 127)
      Bls[0][0][tid] = bias_tab[(size_t)(0 - q0A + tid - 63 + 2047) * 16 + h];
    else if (tid >= 128 && tid < 255)
      Bls[0][1][tid - 128] = bias_tab[(size_t)(0 - q0A - 64 + (tid - 128) - 63 + 2047) * 16 + h];
  }
  __syncthreads();
  bf16x8 qf0 = *(const bf16x8*)(&Qs[t][(ws * 16 + lr) * 72 + lk]);
  bf16x8 qf1 = *(const bf16x8*)(&Qs[t][(ws * 16 + lr) * 72 + 32 + lk]);

  float m_run[4];
  f32x4 lacc = {0.f, 0.f, 0.f, 0.f};
  f32x4 o[4];
#pragma unroll
  for (int r = 0; r < 4; r++) m_run[r] = -1.0e30f;
#pragma unroll
  for (int dt = 0; dt < 4; dt++) o[dt] = f32x4{0.f, 0.f, 0.f, 0.f};

  const int i_base = ws * 16 + lq * 4;
  const float scale2 = 0.125f * LOG2E;   // exp2-domain scale (fused in FMA)

  for (int kc = 0; kc < 2048; kc += 64) {
    const int cn = (kc >> 6) & 1;
    const int nx = cn ^ 1;
    const int kn = kc + 64;
    const bool have_next = (kn < 2048);

    __syncthreads();   // single barrier: publishes stage(n-1); guards overwrites

    // --- issue next-tile global loads (latency covered by QK below) ---
    bf16x8 nk, nv;
    float nb = 0.f;
    if (have_next) {
      nk = *(const bf16x8*)(Kg + (size_t)(kn + ra) * 64 + sa);
      nv = *(const bf16x8*)(Vg + (size_t)ra * 2048 + kn + sa);
      if (tid < 127)
        nb = bias_tab[(size_t)(kn - q0A + tid - 63 + 2047) * 16 + h];
      else if (tid >= 128 && tid < 255)
        nb = bias_tab[(size_t)(kn - q0A - 64 + (tid - 128) - 63 + 2047) * 16 + h];
    }

    // --- QK^T on buffer cn ---
    f32x4 sc[4];
#pragma unroll
    for (int jt = 0; jt < 4; jt++) {
      bf16x8 kb0 = *(const bf16x8*)(&Ks[cn][(jt * 16 + lr) * 72 + lk]);
      bf16x8 kb1 = *(const bf16x8*)(&Ks[cn][(jt * 16 + lr) * 72 + 32 + lk]);
      f32x4 z = {0.f, 0.f, 0.f, 0.f};
      z = MFMA16(qf0, kb0, z);
      z = MFMA16(qf1, kb1, z);
      sc[jt] = z;
    }

    // --- write the staged tile (loads have returned during QK) ---
    if (have_next) {
      *(bf16x8*)(&Ks[nx][ra * 72 + sa]) = nk;
      *(bf16x8*)(&Vs[nx][ra * 72 + sa]) = nv;
      if (tid < 127) Bls[nx][0][tid] = nb;
      else if (tid >= 128 && tid < 255) Bls[nx][1][tid - 128] = nb;
    }

    // --- softmax (exp2 domain) ---
    float mc[4] = {-1.0e30f, -1.0e30f, -1.0e30f, -1.0e30f};
#pragma unroll
    for (int jt = 0; jt < 4; jt++) {
      int base = jt * 16 + lr - i_base + 63;
#pragma unroll
      for (int r = 0; r < 4; r++) {
        float sv = sc[jt][r] * scale2 + Bls[cn][t][base - r];
        sc[jt][r] = sv;
        mc[r] = fmaxf(mc[r], sv);
      }
    }
#pragma unroll
    for (int m = 1; m < 16; m <<= 1)
#pragma unroll
      for (int r = 0; r < 4; r++)
        mc[r] = fmaxf(mc[r], __shfl_xor(mc[r], m));

    float alpha[4];
#pragma unroll
    for (int r = 0; r < 4; r++) {
      float mn = fmaxf(m_run[r], mc[r]);
      alpha[r] = EXP2(m_run[r] - mn);
      m_run[r] = mn;
      lacc[r] *= alpha[r];
    }
#pragma unroll
    for (int jt = 0; jt < 4; jt++)
#pragma unroll
      for (int r = 0; r < 4; r++)
        sc[jt][r] = EXP2(sc[jt][r] - m_run[r]);
#pragma unroll
    for (int dt = 0; dt < 4; dt++)
#pragma unroll
      for (int r = 0; r < 4; r++)
        o[dt][r] *= alpha[r];

    // --- P -> LDS (intra-wave rows only; lgkmcnt orders following reads) ---
#pragma unroll
    for (int jt = 0; jt < 4; jt++)
#pragma unroll
      for (int r = 0; r < 4; r++)
        Ps[t][(ws * 16 + lq * 4 + r) * 72 + jt * 16 + lr] = cvtbf(sc[jt][r]);

    bf16x8 p0 = *(const bf16x8*)(&Ps[t][(ws * 16 + lr) * 72 + lk]);
    bf16x8 p1 = *(const bf16x8*)(&Ps[t][(ws * 16 + lr) * 72 + 32 + lk]);
    // l row-sums via MFMA against all-ones B (same C/D layout as o)
    lacc = MFMA16(p0, onesv, lacc);
    lacc = MFMA16(p1, onesv, lacc);
#pragma unroll
    for (int dt = 0; dt < 4; dt++) {
      bf16x8 v0 = *(const bf16x8*)(&Vs[cn][(dt * 16 + lr) * 72 + lk]);
      bf16x8 v1 = *(const bf16x8*)(&Vs[cn][(dt * 16 + lr) * 72 + 32 + lk]);
      o[dt] = MFMA16(p0, v0, o[dt]);
      o[dt] = MFMA16(p1, v1, o[dt]);
    }
  }

#pragma unroll
  for (int dt = 0; dt < 4; dt++)
#pragma unroll
    for (int r = 0; r < 4; r++) {
      float ov = o[dt][r] / lacc[r];
      int n = q0 + ws * 16 + lq * 4 + r;
      int d = dt * 16 + lr;
      AO[((size_t)b * 2048 + n) * 1024 + h * 64 + d] = cvtbf(ov);
    }
}

// ---------------------------------------------------------------------------
// Output GEMM: AO(4096x1024 bf16) @ WoT^T + bo -> out (fp32).
// 64x128 tiles, grid (64, 8). 2-phase double-buffered async pipeline.
// ---------------------------------------------------------------------------
__global__ __launch_bounds__(256) void out_gemm_k(
    const u16* __restrict__ AO, const u16* __restrict__ WoT,
    const float* __restrict__ bo, float* __restrict__ out) {
  __shared__ __align__(16) u16 As[2][64 * 32];
  __shared__ __align__(16) u16 Bs[2][128 * 32];
  f32x4 acc[4][2];
#pragma unroll
  for (int i = 0; i < 4; i++)
#pragma unroll
    for (int j = 0; j < 2; j++) acc[i][j] = f32x4{0.f, 0.f, 0.f, 0.f};

  const int m0 = blockIdx.x * 64;
  const int n0 = blockIdx.y * 128;
  const int tid  = threadIdx.x;
  const int lane = tid & 63;
  const int wave = tid >> 6;
  const int wc = wave * 32;            // each wave: 64 rows x 32 cols
  const int lr = lane & 15;
  const int lk = (lane >> 4) * 8;
  const int r0 = tid >> 2;
  const int sg = (tid & 3) * 8;

  const u16* ap  = AO + (size_t)(m0 + r0) * 1024 + sg;
  const u16* bp0 = WoT + (size_t)(n0 + r0) * 1024 + sg;
  const u16* bp1 = WoT + (size_t)(n0 + 64 + r0) * 1024 + sg;
  const int ao  = r0 * 32 + sg;        // byte off within buffer = tid*16
  const int bo0 = r0 * 32 + sg;
  const int bo1 = (64 + r0) * 32 + sg;

  async_cp16(&As[0][ao],  ap);
  async_cp16(&Bs[0][bo0], bp0);
  async_cp16(&Bs[0][bo1], bp1);
  __syncthreads();

  int cur = 0;
  for (int k0 = 0; k0 < 1024; k0 += 32) {
    const int nxt = cur ^ 1;
    const int kn = k0 + 32;
    const bool have_next = (kn < 1024);
    if (have_next) {
      async_cp16(&As[nxt][ao],  ap  + kn);
      async_cp16(&Bs[nxt][bo0], bp0 + kn);
      async_cp16(&Bs[nxt][bo1], bp1 + kn);
    }
    bf16x8 af[4], bfv[2];
#pragma unroll
    for (int i = 0; i < 4; i++)
      af[i] = *(const bf16x8*)&As[cur][(i * 16 + lr) * 32 + lk];
#pragma unroll
    for (int j = 0; j < 2; j++)
      bfv[j] = *(const bf16x8*)&Bs[cur][(wc + j * 16 + lr) * 32 + lk];
#pragma unroll
    for (int i = 0; i < 4; i++)
#pragma unroll
      for (int j = 0; j < 2; j++)
        acc[i][j] = MFMA16(af[i], bfv[j], acc[i][j]);
    __syncthreads();   // drains prefetch cp16; all reads of cur complete
    cur = nxt;
  }

  const int orow = (lane >> 4) * 4, ocol = lane & 15;
#pragma unroll
  for (int i = 0; i < 4; i++)
#pragma unroll
    for (int j = 0; j < 2; j++) {
      int gcol = n0 + wc + j * 16 + ocol;
      float bof = bo[gcol];
#pragma unroll
      for (int r = 0; r < 4; r++) {
        int grow = m0 + i * 16 + orow + r;
        out[(size_t)grow * 1024 + gcol] = acc[i][j][r] + bof;   // fp32 store
      }
    }
}

// ---------------------------------------------------------------------------
extern "C" void kernel_launch(void* const* d_in, const int* in_sizes, int n_in,
                              void* d_out, int out_size, void* d_ws, size_t ws_size,
                              hipStream_t stream) {
  const float* x    = (const float*)d_in[0];
  const float* Wq   = (const float*)d_in[1];
  const float* Wkv  = (const float*)d_in[2];
  const float* Wo   = (const float*)d_in[3];
  const float* bo   = (const float*)d_in[4];
  const float* rel  = (const float*)d_in[5];
  float* out = (float*)d_out;                 // fp32 output

  char* ws = (char*)d_ws;
  u16*   WoT  = (u16*)(ws + 0);          //  2 MB
  float* btab = (float*)(ws + 2097152);  //  0.25 MB
  u16*   Qb   = (u16*)(ws + 2359296);    //  8 MB
  u16*   Kbuf = (u16*)(ws + 10747904);   //  8 MB
  u16*   VTb  = (u16*)(ws + 19136512);   //  8 MB
  u16*   AO   = (u16*)(ws + 27525120);   //  8 MB
  u16*   Wall = AO;                      //  6 MB alias (dead before attn)
  u16*   Xb   = (u16*)(ws + 35913728);   //  8 MB (only if ws_size allows)
  const bool fast = (ws_size >= (size_t)35913728 + 8388608);

  bias_table_k<<<16, 256, 0, stream>>>(rel, btab);
  transpose_all_k<<<dim3(32, 32, 4), dim3(32, 8), 0, stream>>>(Wq, Wkv, Wo, Wall, WoT);

  if (fast) {
    xcvt_k<<<2048, 256, 0, stream>>>(x, Xb);
    proj_gemm_bf16_k<<<dim3(32, 24), 256, 0, stream>>>(Xb, Wall, Qb, Kbuf, VTb);
  } else {
    proj_gemm_f32_k<<<dim3(32, 24), 256, 0, stream>>>(x, Wall, Qb, Kbuf, VTb);
  }

  attn_k<<<dim3(16, 32), 512, 0, stream>>>(Qb, Kbuf, VTb, btab, AO);
  out_gemm_k<<<dim3(64, 8), 256, 0, stream>>>(AO, WoT, bo, out);
}

// Round 18
// 240.989 us; speedup vs baseline: 1.0233x; 1.0233x over previous
//
#include <hip/hip_runtime.h>

typedef unsigned short u16;
typedef __attribute__((ext_vector_type(8))) __bf16 bf16x8;
typedef __attribute__((ext_vector_type(4))) float f32x4;

#define MFMA16(a, b, c) __builtin_amdgcn_mfma_f32_16x16x32_bf16((a), (b), (c), 0, 0, 0)

#if __has_builtin(__builtin_amdgcn_exp2f)
#define EXP2(x) __builtin_amdgcn_exp2f(x)
#else
#define EXP2(x) exp2f(x)
#endif
#define LOG2E 1.44269504088896f

__device__ __forceinline__ u16 f2bf(float f) {
  union { float f; unsigned u; } c; c.f = f;
  unsigned u = c.u;
  u += 0x7FFFu + ((u >> 16) & 1u);   // round-to-nearest-even
  return (u16)(u >> 16);
}

// native float->bf16 (compiler lowers to HW cvt, RTNE)
__device__ __forceinline__ u16 cvtbf(float f) {
  union { __bf16 b; u16 u; } c;
  c.b = (__bf16)f;
  return c.u;
}

__device__ __forceinline__ bf16x8 pack8(const float4& a, const float4& b) {
  union { u16 u[8]; bf16x8 v; } r;
  r.u[0] = f2bf(a.x); r.u[1] = f2bf(a.y); r.u[2] = f2bf(a.z); r.u[3] = f2bf(a.w);
  r.u[4] = f2bf(b.x); r.u[5] = f2bf(b.y); r.u[6] = f2bf(b.z); r.u[7] = f2bf(b.w);
  return r.v;
}

// async global->LDS, 16 bytes/lane (LDS dest = base + tid*16, m104 constraint).
__device__ __forceinline__ void async_cp16(u16* l, const u16* g) {
  __builtin_amdgcn_global_load_lds(
      (const __attribute__((address_space(1))) unsigned int*)g,
      (__attribute__((address_space(3))) unsigned int*)l, 16, 0, 0);
}

// ---------------------------------------------------------------------------
// Fused prologue: ONE launch for all prep work (was 3 launches).
//   z=0..3 : weight transpose+cvt slices (math identical to transpose_all_k)
//   z=4..5 : X fp32 -> bf16 halves (math identical to xcvt_k); skipped if !do_x
//   z=6    : T5 bias table xLOG2E (blocks 0..15 active; math identical)
// Grid (32, 32, 7), block (32, 8).
// ---------------------------------------------------------------------------
__global__ __launch_bounds__(256) void prep_k(
    const float* __restrict__ Wq, const float* __restrict__ Wkv,
    const float* __restrict__ Wo, const float* __restrict__ Xf,
    const float* __restrict__ rel_emb,
    u16* __restrict__ Wall, u16* __restrict__ WoT,
    u16* __restrict__ Xb, float* __restrict__ btab, int do_x) {
  __shared__ u16 t[32][33];
  const int z = blockIdx.z;

  if (z < 4) {
    const float* src; u16* dst; int C_ld, col0;
    if (z == 0)      { src = Wo;  dst = WoT;                C_ld = 1024; col0 = 0; }
    else if (z == 1) { src = Wq;  dst = Wall;               C_ld = 1024; col0 = 0; }
    else if (z == 2) { src = Wkv; dst = Wall + 1024 * 1024; C_ld = 2048; col0 = 0; }
    else             { src = Wkv; dst = Wall + 2048 * 1024; C_ld = 2048; col0 = 1024; }
    const int bx = blockIdx.x * 32;
    const int by = blockIdx.y * 32;
    const int tx = threadIdx.x;
    for (int yo = threadIdx.y; yo < 32; yo += 8)
      t[yo][tx] = f2bf(src[(size_t)(by + yo) * C_ld + col0 + bx + tx]);
    __syncthreads();
    for (int yo = threadIdx.y; yo < 32; yo += 8)
      dst[(size_t)(bx + yo) * 1024 + by + tx] = t[tx][yo];
  } else if (z < 6) {
    if (!do_x) return;
    const int bid = blockIdx.y * 32 + blockIdx.x;            // 0..1023
    const int tl  = threadIdx.y * 32 + threadIdx.x;          // 0..255
    const size_t i = (((size_t)(z - 4) * 1024 + bid) * 256 + tl) * 8;
    float4 a = *(const float4*)(Xf + i);
    float4 b = *(const float4*)(Xf + i + 4);
    *(bf16x8*)(Xb + i) = pack8(a, b);
  } else {
    const int bid = blockIdx.y * 32 + blockIdx.x;
    if (bid >= 16) return;
    const int tl = threadIdx.y * 32 + threadIdx.x;
    const int idx = bid * 256 + tl;
    if (idx >= 4095) return;
    int delta = idx - 2047;   // j - i
    int n = -delta;           // i - j
    int ret = 0;
    if (n < 0) { ret = 16; n = -n; }
    int bucket;
    if (n < 8) {
      bucket = n;
    } else {
      int vl = 8 + (int)(2.0f * __log2f((float)n * 0.125f));
      bucket = vl < 15 ? vl : 15;
    }
    bucket += ret;
#pragma unroll
    for (int h = 0; h < 16; h++)
      btab[(size_t)idx * 16 + h] = rel_emb[bucket * 16 + h] * LOG2E;
  }
}

// ---------------------------------------------------------------------------
// Shared epilogue for both proj variants.
// ---------------------------------------------------------------------------
__device__ __forceinline__ void proj_epilogue(
    const f32x4 (&acc)[4][4], int m0, int n0, int wr, int wc, int lane,
    u16* dstQ, u16* dstK, u16* dstVT) {
  const int orow = (lane >> 4) * 4, ocol = lane & 15;
#pragma unroll
  for (int i = 0; i < 4; i++)
#pragma unroll
    for (int j = 0; j < 4; j++)
#pragma unroll
      for (int r = 0; r < 4; r++) {
        int grow = m0 + wr + i * 16 + orow + r;   // token
        int gcol = n0 + wc + j * 16 + ocol;       // fused channel 0..3071
        int b = grow >> 11, n = grow & 2047;
        int seg = gcol >> 10;                     // 0=Q, 1=K, 2=V (uniform/block)
        int c = gcol & 1023;
        int h = c >> 6, d = c & 63;
        u16 bv = f2bf(acc[i][j][r]);
        if (seg == 0)
          dstQ[(((size_t)b * 16 + h) * 2048 + n) * 64 + d] = bv;
        else if (seg == 1)
          dstK[(((size_t)b * 16 + h) * 2048 + n) * 64 + d] = bv;
        else
          dstVT[(((size_t)b * 16 + h) * 64 + d) * 2048 + n] = bv;
      }
}

// ---------------------------------------------------------------------------
// Fast projection GEMM: Xb(4096x1024 bf16, pre-converted) @ Wall^T.
// ---------------------------------------------------------------------------
__global__ __launch_bounds__(256) void proj_gemm_bf16_k(
    const u16* __restrict__ Xb, const u16* __restrict__ WT,
    u16* __restrict__ dstQ, u16* __restrict__ dstK, u16* __restrict__ dstVT) {
  __shared__ __align__(16) u16 As[2][128 * 32];
  __shared__ __align__(16) u16 Bs[2][128 * 32];
  f32x4 acc[4][4];
#pragma unroll
  for (int i = 0; i < 4; i++)
#pragma unroll
    for (int j = 0; j < 4; j++) acc[i][j] = f32x4{0.f, 0.f, 0.f, 0.f};

  const int m0 = blockIdx.x * 128;
  const int n0 = blockIdx.y * 128;
  const int tid  = threadIdx.x;
  const int lane = tid & 63;
  const int wave = tid >> 6;
  const int wr = (wave >> 1) * 64;
  const int wc = (wave & 1) * 64;
  const int lr = lane & 15;
  const int lk = (lane >> 4) * 8;
  const int r0 = tid >> 2;
  const int sg = (tid & 3) * 8;

  const u16* xp0 = Xb + (size_t)(m0 + r0) * 1024 + sg;
  const u16* xp1 = Xb + (size_t)(m0 + 64 + r0) * 1024 + sg;
  const u16* bp0 = WT + (size_t)(n0 + r0) * 1024 + sg;
  const u16* bp1 = WT + (size_t)(n0 + 64 + r0) * 1024 + sg;
  const int ao0 = r0 * 32 + sg;            // byte off within buffer = tid*16
  const int ao1 = (64 + r0) * 32 + sg;
  const int bo0 = ao0, bo1 = ao1;

  async_cp16(&As[0][ao0], xp0);
  async_cp16(&As[0][ao1], xp1);
  async_cp16(&Bs[0][bo0], bp0);
  async_cp16(&Bs[0][bo1], bp1);
  __syncthreads();

  int cur = 0;
  for (int k0 = 0; k0 < 1024; k0 += 32) {
    const int nxt = cur ^ 1;
    const int kn = k0 + 32;
    const bool have_next = (kn < 1024);
    if (have_next) {
      async_cp16(&As[nxt][ao0], xp0 + kn);
      async_cp16(&As[nxt][ao1], xp1 + kn);
      async_cp16(&Bs[nxt][bo0], bp0 + kn);
      async_cp16(&Bs[nxt][bo1], bp1 + kn);
    }
    bf16x8 af[4], bfv[4];
#pragma unroll
    for (int i = 0; i < 4; i++)
      af[i] = *(const bf16x8*)&As[cur][(wr + i * 16 + lr) * 32 + lk];
#pragma unroll
    for (int j = 0; j < 4; j++)
      bfv[j] = *(const bf16x8*)&Bs[cur][(wc + j * 16 + lr) * 32 + lk];
#pragma unroll
    for (int i = 0; i < 4; i++)
#pragma unroll
      for (int j = 0; j < 4; j++)
        acc[i][j] = MFMA16(af[i], bfv[j], acc[i][j]);
    __syncthreads();
    cur = nxt;
  }
  proj_epilogue(acc, m0, n0, wr, wc, lane, dstQ, dstK, dstVT);
}

// ---------------------------------------------------------------------------
// Fallback projection GEMM (verified): Xf fp32 A-path with pack8 staging.
// ---------------------------------------------------------------------------
__global__ __launch_bounds__(256) void proj_gemm_f32_k(
    const float* __restrict__ Xf, const u16* __restrict__ WT,
    u16* __restrict__ dstQ, u16* __restrict__ dstK, u16* __restrict__ dstVT) {
  __shared__ __align__(16) u16 As[2][128 * 32];
  __shared__ __align__(16) u16 Bs[2][128 * 32];
  f32x4 acc[4][4];
#pragma unroll
  for (int i = 0; i < 4; i++)
#pragma unroll
    for (int j = 0; j < 4; j++) acc[i][j] = f32x4{0.f, 0.f, 0.f, 0.f};

  const int m0 = blockIdx.x * 128;
  const int n0 = blockIdx.y * 128;
  const int tid  = threadIdx.x;
  const int lane = tid & 63;
  const int wave = tid >> 6;
  const int wr = (wave >> 1) * 64;
  const int wc = (wave & 1) * 64;
  const int lr = lane & 15;
  const int lk = (lane >> 4) * 8;
  const int r0 = tid >> 2;
  const int sg = (tid & 3) * 8;

  const float* ap0 = Xf + (size_t)(m0 + r0) * 1024 + sg;
  const float* ap1 = Xf + (size_t)(m0 + 64 + r0) * 1024 + sg;
  const u16* bp0 = WT + (size_t)(n0 + r0) * 1024 + sg;
  const u16* bp1 = WT + (size_t)(n0 + 64 + r0) * 1024 + sg;
  const int ao0 = r0 * 32 + sg;
  const int ao1 = (64 + r0) * 32 + sg;
  const int bo0 = ao0, bo1 = ao1;

  async_cp16(&Bs[0][bo0], bp0);
  async_cp16(&Bs[0][bo1], bp1);
  {
    float4 a00 = *(const float4*)(ap0);
    float4 a01 = *(const float4*)(ap0 + 4);
    float4 a10 = *(const float4*)(ap1);
    float4 a11 = *(const float4*)(ap1 + 4);
    *(bf16x8*)&As[0][ao0] = pack8(a00, a01);
    *(bf16x8*)&As[0][ao1] = pack8(a10, a11);
  }
  __syncthreads();

  int cur = 0;
  for (int k0 = 0; k0 < 1024; k0 += 32) {
    const int nxt = cur ^ 1;
    const int kn = k0 + 32;
    const bool have_next = (kn < 1024);
    float4 a00, a01, a10, a11;
    if (have_next) {
      async_cp16(&Bs[nxt][bo0], bp0 + kn);
      async_cp16(&Bs[nxt][bo1], bp1 + kn);
      a00 = *(const float4*)(ap0 + kn);
      a01 = *(const float4*)(ap0 + kn + 4);
      a10 = *(const float4*)(ap1 + kn);
      a11 = *(const float4*)(ap1 + kn + 4);
    }
    bf16x8 af[4], bfv[4];
#pragma unroll
    for (int i = 0; i < 4; i++)
      af[i] = *(const bf16x8*)&As[cur][(wr + i * 16 + lr) * 32 + lk];
#pragma unroll
    for (int j = 0; j < 4; j++)
      bfv[j] = *(const bf16x8*)&Bs[cur][(wc + j * 16 + lr) * 32 + lk];
#pragma unroll
    for (int i = 0; i < 4; i++)
#pragma unroll
      for (int j = 0; j < 4; j++)
        acc[i][j] = MFMA16(af[i], bfv[j], acc[i][j]);
    if (have_next) {
      *(bf16x8*)&As[nxt][ao0] = pack8(a00, a01);
      *(bf16x8*)&As[nxt][ao1] = pack8(a10, a11);
    }
    __syncthreads();
    cur = nxt;
  }
  proj_epilogue(acc, m0, n0, wr, wc, lane, dstQ, dstK, dstVT);
}

// ---------------------------------------------------------------------------
// Flash attention with T5 bias — EXACT R16 body (verified 102.2 µs,
// absmax 2.197e-3). Saturated-bias fast path permanently abandoned after
// 4 independent correctness failures (R1/R2/R3/R17) despite an apparently
// airtight equivalence argument; mechanism unresolved.
// ---------------------------------------------------------------------------
__global__ __launch_bounds__(512) void attn_k(
    const u16* __restrict__ Q, const u16* __restrict__ Kb,
    const u16* __restrict__ VT, const float* __restrict__ bias_tab,
    u16* __restrict__ AO) {
  const int tid = threadIdx.x;                  // 0..511
  const int lane = tid & 63, wave = tid >> 6;   // wave 0..7
  const int t = wave >> 2;                      // q-subtile 0/1
  const int ws = wave & 3;                      // wave index within tile
  const int lr = lane & 15, lq = lane >> 4, lk = lq * 8;
  const int bh = blockIdx.y, b = bh >> 4, h = bh & 15;
  const int q0A = blockIdx.x * 128;             // tile-0 origin
  const int q0 = q0A + t * 64;                  // this wave's tile origin

  __shared__ __align__(16) u16 Qs[2][64 * 72];  // reused as Ps after Q-frag read
  __shared__ __align__(16) u16 Ks[2][64 * 72];  // [buf]
  __shared__ __align__(16) u16 Vs[2][64 * 72];  // [buf]
  __shared__ float Bls[2][2][128];              // [buf][tile]
  u16 (*Ps)[64 * 72] = Qs;

  const u16* Qg = Q + ((size_t)bh * 2048 + q0A) * 64;
  const u16* Kg = Kb + (size_t)bh * 2048 * 64;
  const u16* Vg = VT + (size_t)bh * 64 * 2048;
  const int ra = tid >> 3, sa = (tid & 7) * 8;

  // all-ones B fragment for the MFMA row-sum (bf16 1.0 = 0x3F80)
  union { u16 u[8]; bf16x8 v; } onesc;
#pragma unroll
  for (int i = 0; i < 8; i++) onesc.u[i] = 0x3F80;
  const bf16x8 onesv = onesc.v;

  // --- prologue: stage Q (both tiles) and K/V/Bls buffer 0 ---
  {
    int c1 = tid + 512;
    int r1_ = c1 >> 3, s1_ = (c1 & 7) * 8;      // r1_ 64..127 (tile 1)
    *(bf16x8*)(&Qs[0][ra * 72 + sa])          = *(const bf16x8*)(Qg + (size_t)ra * 64 + sa);
    *(bf16x8*)(&Qs[1][(r1_ - 64) * 72 + s1_]) = *(const bf16x8*)(Qg + (size_t)r1_ * 64 + s1_);
    *(bf16x8*)(&Ks[0][ra * 72 + sa]) = *(const bf16x8*)(Kg + (size_t)ra * 64 + sa);
    *(bf16x8*)(&Vs[0][ra * 72 + sa]) = *(const bf16x8*)(Vg + (size_t)ra * 2048 + sa);
    if (tid < 127)
      Bls[0][0][tid] = bias_tab[(size_t)(0 - q0A + tid - 63 + 2047) * 16 + h];
    else if (tid >= 128 && tid < 255)
      Bls[0][1][tid - 128] = bias_tab[(size_t)(0 - q0A - 64 + (tid - 128) - 63 + 2047) * 16 + h];
  }
  __syncthreads();
  bf16x8 qf0 = *(const bf16x8*)(&Qs[t][(ws * 16 + lr) * 72 + lk]);
  bf16x8 qf1 = *(const bf16x8*)(&Qs[t][(ws * 16 + lr) * 72 + 32 + lk]);

  float m_run[4];
  f32x4 lacc = {0.f, 0.f, 0.f, 0.f};
  f32x4 o[4];
#pragma unroll
  for (int r = 0; r < 4; r++) m_run[r] = -1.0e30f;
#pragma unroll
  for (int dt = 0; dt < 4; dt++) o[dt] = f32x4{0.f, 0.f, 0.f, 0.f};

  const int i_base = ws * 16 + lq * 4;
  const float scale2 = 0.125f * LOG2E;   // exp2-domain scale (fused in FMA)

  for (int kc = 0; kc < 2048; kc += 64) {
    const int cn = (kc >> 6) & 1;
    const int nx = cn ^ 1;
    const int kn = kc + 64;
    const bool have_next = (kn < 2048);

    __syncthreads();   // single barrier: publishes stage(n-1); guards overwrites

    // --- issue next-tile global loads (latency covered by QK below) ---
    bf16x8 nk, nv;
    float nb = 0.f;
    if (have_next) {
      nk = *(const bf16x8*)(Kg + (size_t)(kn + ra) * 64 + sa);
      nv = *(const bf16x8*)(Vg + (size_t)ra * 2048 + kn + sa);
      if (tid < 127)
        nb = bias_tab[(size_t)(kn - q0A + tid - 63 + 2047) * 16 + h];
      else if (tid >= 128 && tid < 255)
        nb = bias_tab[(size_t)(kn - q0A - 64 + (tid - 128) - 63 + 2047) * 16 + h];
    }

    // --- QK^T on buffer cn ---
    f32x4 sc[4];
#pragma unroll
    for (int jt = 0; jt < 4; jt++) {
      bf16x8 kb0 = *(const bf16x8*)(&Ks[cn][(jt * 16 + lr) * 72 + lk]);
      bf16x8 kb1 = *(const bf16x8*)(&Ks[cn][(jt * 16 + lr) * 72 + 32 + lk]);
      f32x4 z = {0.f, 0.f, 0.f, 0.f};
      z = MFMA16(qf0, kb0, z);
      z = MFMA16(qf1, kb1, z);
      sc[jt] = z;
    }

    // --- write the staged tile (loads have returned during QK) ---
    if (have_next) {
      *(bf16x8*)(&Ks[nx][ra * 72 + sa]) = nk;
      *(bf16x8*)(&Vs[nx][ra * 72 + sa]) = nv;
      if (tid < 127) Bls[nx][0][tid] = nb;
      else if (tid >= 128 && tid < 255) Bls[nx][1][tid - 128] = nb;
    }

    // --- softmax (exp2 domain) ---
    float mc[4] = {-1.0e30f, -1.0e30f, -1.0e30f, -1.0e30f};
#pragma unroll
    for (int jt = 0; jt < 4; jt++) {
      int base = jt * 16 + lr - i_base + 63;
#pragma unroll
      for (int r = 0; r < 4; r++) {
        float sv = sc[jt][r] * scale2 + Bls[cn][t][base - r];
        sc[jt][r] = sv;
        mc[r] = fmaxf(mc[r], sv);
      }
    }
#pragma unroll
    for (int m = 1; m < 16; m <<= 1)
#pragma unroll
      for (int r = 0; r < 4; r++)
        mc[r] = fmaxf(mc[r], __shfl_xor(mc[r], m));

    float alpha[4];
#pragma unroll
    for (int r = 0; r < 4; r++) {
      float mn = fmaxf(m_run[r], mc[r]);
      alpha[r] = EXP2(m_run[r] - mn);
      m_run[r] = mn;
      lacc[r] *= alpha[r];
    }
#pragma unroll
    for (int jt = 0; jt < 4; jt++)
#pragma unroll
      for (int r = 0; r < 4; r++)
        sc[jt][r] = EXP2(sc[jt][r] - m_run[r]);
#pragma unroll
    for (int dt = 0; dt < 4; dt++)
#pragma unroll
      for (int r = 0; r < 4; r++)
        o[dt][r] *= alpha[r];

    // --- P -> LDS (intra-wave rows only; lgkmcnt orders following reads) ---
#pragma unroll
    for (int jt = 0; jt < 4; jt++)
#pragma unroll
      for (int r = 0; r < 4; r++)
        Ps[t][(ws * 16 + lq * 4 + r) * 72 + jt * 16 + lr] = cvtbf(sc[jt][r]);

    bf16x8 p0 = *(const bf16x8*)(&Ps[t][(ws * 16 + lr) * 72 + lk]);
    bf16x8 p1 = *(const bf16x8*)(&Ps[t][(ws * 16 + lr) * 72 + 32 + lk]);
    // l row-sums via MFMA against all-ones B (same C/D layout as o)
    lacc = MFMA16(p0, onesv, lacc);
    lacc = MFMA16(p1, onesv, lacc);
#pragma unroll
    for (int dt = 0; dt < 4; dt++) {
      bf16x8 v0 = *(const bf16x8*)(&Vs[cn][(dt * 16 + lr) * 72 + lk]);
      bf16x8 v1 = *(const bf16x8*)(&Vs[cn][(dt * 16 + lr) * 72 + 32 + lk]);
      o[dt] = MFMA16(p0, v0, o[dt]);
      o[dt] = MFMA16(p1, v1, o[dt]);
    }
  }

#pragma unroll
  for (int dt = 0; dt < 4; dt++)
#pragma unroll
    for (int r = 0; r < 4; r++) {
      float ov = o[dt][r] / lacc[r];
      int n = q0 + ws * 16 + lq * 4 + r;
      int d = dt * 16 + lr;
      AO[((size_t)b * 2048 + n) * 1024 + h * 64 + d] = cvtbf(ov);
    }
}

// ---------------------------------------------------------------------------
// Output GEMM: AO(4096x1024 bf16) @ WoT^T + bo -> out (fp32).
// 64x128 tiles, grid (64, 8). 2-phase double-buffered async pipeline.
// ---------------------------------------------------------------------------
__global__ __launch_bounds__(256) void out_gemm_k(
    const u16* __restrict__ AO, const u16* __restrict__ WoT,
    const float* __restrict__ bo, float* __restrict__ out) {
  __shared__ __align__(16) u16 As[2][64 * 32];
  __shared__ __align__(16) u16 Bs[2][128 * 32];
  f32x4 acc[4][2];
#pragma unroll
  for (int i = 0; i < 4; i++)
#pragma unroll
    for (int j = 0; j < 2; j++) acc[i][j] = f32x4{0.f, 0.f, 0.f, 0.f};

  const int m0 = blockIdx.x * 64;
  const int n0 = blockIdx.y * 128;
  const int tid  = threadIdx.x;
  const int lane = tid & 63;
  const int wave = tid >> 6;
  const int wc = wave * 32;            // each wave: 64 rows x 32 cols
  const int lr = lane & 15;
  const int lk = (lane >> 4) * 8;
  const int r0 = tid >> 2;
  const int sg = (tid & 3) * 8;

  const u16* ap  = AO + (size_t)(m0 + r0) * 1024 + sg;
  const u16* bp0 = WoT + (size_t)(n0 + r0) * 1024 + sg;
  const u16* bp1 = WoT + (size_t)(n0 + 64 + r0) * 1024 + sg;
  const int ao  = r0 * 32 + sg;        // byte off within buffer = tid*16
  const int bo0 = r0 * 32 + sg;
  const int bo1 = (64 + r0) * 32 + sg;

  async_cp16(&As[0][ao],  ap);
  async_cp16(&Bs[0][bo0], bp0);
  async_cp16(&Bs[0][bo1], bp1);
  __syncthreads();

  int cur = 0;
  for (int k0 = 0; k0 < 1024; k0 += 32) {
    const int nxt = cur ^ 1;
    const int kn = k0 + 32;
    const bool have_next = (kn < 1024);
    if (have_next) {
      async_cp16(&As[nxt][ao],  ap  + kn);
      async_cp16(&Bs[nxt][bo0], bp0 + kn);
      async_cp16(&Bs[nxt][bo1], bp1 + kn);
    }
    bf16x8 af[4], bfv[2];
#pragma unroll
    for (int i = 0; i < 4; i++)
      af[i] = *(const bf16x8*)&As[cur][(i * 16 + lr) * 32 + lk];
#pragma unroll
    for (int j = 0; j < 2; j++)
      bfv[j] = *(const bf16x8*)&Bs[cur][(wc + j * 16 + lr) * 32 + lk];
#pragma unroll
    for (int i = 0; i < 4; i++)
#pragma unroll
      for (int j = 0; j < 2; j++)
        acc[i][j] = MFMA16(af[i], bfv[j], acc[i][j]);
    __syncthreads();   // drains prefetch cp16; all reads of cur complete
    cur = nxt;
  }

  const int orow = (lane >> 4) * 4, ocol = lane & 15;
#pragma unroll
  for (int i = 0; i < 4; i++)
#pragma unroll
    for (int j = 0; j < 2; j++) {
      int gcol = n0 + wc + j * 16 + ocol;
      float bof = bo[gcol];
#pragma unroll
      for (int r = 0; r < 4; r++) {
        int grow = m0 + i * 16 + orow + r;
        out[(size_t)grow * 1024 + gcol] = acc[i][j][r] + bof;   // fp32 store
      }
    }
}

// ---------------------------------------------------------------------------
extern "C" void kernel_launch(void* const* d_in, const int* in_sizes, int n_in,
                              void* d_out, int out_size, void* d_ws, size_t ws_size,
                              hipStream_t stream) {
  const float* x    = (const float*)d_in[0];
  const float* Wq   = (const float*)d_in[1];
  const float* Wkv  = (const float*)d_in[2];
  const float* Wo   = (const float*)d_in[3];
  const float* bo   = (const float*)d_in[4];
  const float* rel  = (const float*)d_in[5];
  float* out = (float*)d_out;                 // fp32 output

  char* ws = (char*)d_ws;
  u16*   WoT  = (u16*)(ws + 0);          //  2 MB
  float* btab = (float*)(ws + 2097152);  //  0.25 MB
  u16*   Qb   = (u16*)(ws + 2359296);    //  8 MB
  u16*   Kbuf = (u16*)(ws + 10747904);   //  8 MB
  u16*   VTb  = (u16*)(ws + 19136512);   //  8 MB
  u16*   AO   = (u16*)(ws + 27525120);   //  8 MB
  u16*   Wall = AO;                      //  6 MB alias (dead before attn)
  u16*   Xb   = (u16*)(ws + 35913728);   //  8 MB (only if ws_size allows)
  const bool fast = (ws_size >= (size_t)35913728 + 8388608);

  // ONE prologue launch: 4 weight transposes + X cvt + bias table
  prep_k<<<dim3(32, 32, 7), dim3(32, 8), 0, stream>>>(
      Wq, Wkv, Wo, x, rel, Wall, WoT, Xb, btab, fast ? 1 : 0);

  if (fast) {
    proj_gemm_bf16_k<<<dim3(32, 24), 256, 0, stream>>>(Xb, Wall, Qb, Kbuf, VTb);
  } else {
    proj_gemm_f32_k<<<dim3(32, 24), 256, 0, stream>>>(x, Wall, Qb, Kbuf, VTb);
  }

  attn_k<<<dim3(16, 32), 512, 0, stream>>>(Qb, Kbuf, VTb, btab, AO);
  out_gemm_k<<<dim3(64, 8), 256, 0, stream>>>(AO, WoT, bo, out);
}